// Round 1
// baseline (1100.418 us; speedup 1.0000x reference)
//
#include <hip/hip_runtime.h>

typedef _Float16 f16;
typedef _Float16 half8 __attribute__((ext_vector_type(8)));
typedef float f32x4 __attribute__((ext_vector_type(4)));

#define ROWS 64
#define XSTR 616   // halfs per row of layer-0 input tile (608 used + pad, 2-way bank aliasing only)
#define HSTR 264   // halfs per row of hidden activation tiles (256 used + pad)
#define NTHREADS 512

// packed-weight byte offsets in d_ws:
// L0: [76][256][8] f16 = 311296 B ; L1..L3: [32][256][8] = 131072 B each ; L4: [32][16][8] = 8192 B
// total = 712704 B
#define WP_TOTAL_HALFS 356352

__device__ __forceinline__ void gload_lds16(const void* g, void* l) {
    __builtin_amdgcn_global_load_lds(
        (const __attribute__((address_space(1))) unsigned int*)g,
        (__attribute__((address_space(3))) unsigned int*)l, 16, 0, 0);
}

__global__ void prep_weights(const float* __restrict__ W0, const float* __restrict__ W1,
                             const float* __restrict__ W2, const float* __restrict__ W3,
                             const float* __restrict__ W4, f16* __restrict__ wp) {
    int idx = blockIdx.x * 256 + threadIdx.x;
    if (idx >= WP_TOTAL_HALFS) return;
    float v = 0.f;
    if (idx < 155648) {                       // L0: k0 in [0,76), N=256
        int k0 = idx >> 11;                   // /(256*8)
        int rem = idx & 2047;
        int n = rem >> 3, j = rem & 7;
        int k = k0 * 8 + j;
        if (k < 587) v = W0[k * 256 + n];
    } else if (idx < 352256) {                // L1..L3
        int local = idx - 155648;
        int l = local >> 16;                  // /65536
        int ll = local & 65535;
        int k0 = ll >> 11;
        int rem = ll & 2047;
        int n = rem >> 3, j = rem & 7;
        int k = k0 * 8 + j;
        const float* W = (l == 0) ? W1 : (l == 1) ? W2 : W3;
        v = W[k * 256 + n];
    } else {                                  // L4: N padded 3->16
        int local = idx - 352256;
        int k0 = local >> 7;                  // /(16*8)
        int rem = local & 127;
        int n = rem >> 3, j = rem & 7;
        int k = k0 * 8 + j;
        if (n < 3) v = W4[k * 3 + n];
    }
    wp[idx] = (f16)v;
}

__global__ __launch_bounds__(NTHREADS, 1)
void liif_kernel(const float* __restrict__ feat,    // [64][128][128]
                 const float* __restrict__ mask,    // [128][128]
                 const float* __restrict__ coord,   // [65536][2]
                 const float* __restrict__ b0, const float* __restrict__ b1,
                 const float* __restrict__ b2, const float* __restrict__ b3,
                 const float* __restrict__ b4,
                 const f16* __restrict__ wp,
                 float* __restrict__ out)            // [3][256][256]
{
    __shared__ __align__(16) f16 sX[ROWS * XSTR];    // 78848 B (layer-0 input; reused as act buffer)
    __shared__ __align__(16) f16 sH[ROWS * HSTR];    // 33792 B
    __shared__ __align__(16) f16 sW[2][8192];        // 2 x 16384 B weight chunk double-buffer
    __shared__ float sArea[ROWS];
    __shared__ int   sIY[ROWS], sIX[ROWS];
    __shared__ float sPred[ROWS * 4];

    const int tid = threadIdx.x;
    const int wv  = tid >> 6;
    const int ln  = tid & 63;
    const int lo  = ln & 15;
    const int hi  = ln >> 4;

    // ---- issue stage of chunk 0 (L0 ks=0) immediately ----
    {
        const char* srcp = (const char*)wp;         // WOFF0 = 0
        char* dstp = (char*)&sW[0][0];
        for (int off = wv * 1024; off < 16384; off += 8192)
            gload_lds16(srcp + off + (ln << 4), dstp + off);
    }

    // ---- meta: replicate reference index math exactly in fp32 ----
    if (tid < ROWS) {
        int r = tid;
        int R = blockIdx.x * ROWS + r;
        int q = R >> 2, s = R & 3;
        float c0 = coord[q * 2 + 0];
        float c1 = coord[q * 2 + 1];
        float vx = (s & 2) ? 1.0f : -1.0f;
        float vy = (s & 1) ? 1.0f : -1.0f;
        const float rxy = 0.0078125f;               // 1/128 exact
        const float LOC = (float)(-1.0 + 1e-6);
        const float HIC = (float)( 1.0 - 1e-6);
        float cy = fminf(fmaxf(c0 + vx * rxy + 1e-6f, LOC), HIC);
        float cx = fminf(fmaxf(c1 + vy * rxy + 1e-6f, LOC), HIC);
        int iy = (int)rintf(((cy + 1.0f) * 128.0f - 1.0f) * 0.5f);
        int ix = (int)rintf(((cx + 1.0f) * 128.0f - 1.0f) * 0.5f);
        iy = min(max(iy, 0), 127);
        ix = min(max(ix, 0), 127);
        float qy = -1.0f + ((float)(2 * iy) + 1.0f) * rxy;
        float qx = -1.0f + ((float)(2 * ix) + 1.0f) * rxy;
        float rel0 = (c0 - qy) * 128.0f;
        float rel1 = (c1 - qx) * 128.0f;
        sIY[r] = iy; sIX[r] = ix;
        sArea[r] = fabsf(rel0 * rel1) + 1e-9f;
        sX[r * XSTR + 585] = (f16)rel0;
        sX[r * XSTR + 586] = (f16)rel1;
        for (int k = 587; k < 608; ++k) sX[r * XSTR + k] = (f16)0.f;
    }
    __syncthreads();   // meta visible; chunk0 drained

    // ---- gather 3x3 unfold features -> sX (f16) ----
    for (int idx = tid; idx < ROWS * 585; idx += NTHREADS) {
        int r = idx / 585;
        int k = idx - r * 585;
        int c = k / 9;
        int o = k - c * 9;
        int ki = o / 3;
        int kj = o - ki * 3;
        int yy = sIY[r] + ki - 1;
        int xx = sIX[r] + kj - 1;
        float v = 0.f;
        if ((unsigned)yy < 128u && (unsigned)xx < 128u) {
            v = (c < 64) ? feat[(c << 14) + (yy << 7) + xx] : mask[(yy << 7) + xx];
        }
        sX[r * XSTR + k] = (f16)v;
    }
    __syncthreads();

    // ---- fused 5-layer MLP ----
    f16* src_act = sX; int src_str = XSTR;
    f16* dst_act = sH;
    int cur = 0;

    for (int layer = 0; layer < 5; ++layer) {
        const int nk = (layer == 0) ? 19 : 8;
        f32x4 acc[4][2];
        #pragma unroll
        for (int m = 0; m < 4; ++m) {
            acc[m][0] = f32x4{0.f, 0.f, 0.f, 0.f};
            acc[m][1] = f32x4{0.f, 0.f, 0.f, 0.f};
        }

        for (int ks = 0; ks < nk; ++ks) {
            // stage next chunk into sW[cur^1] (stays in flight during compute)
            bool have_next = !(layer == 4 && ks == nk - 1);
            if (have_next) {
                int nl = layer, nks = ks + 1;
                if (nks == nk) { nl = layer + 1; nks = 0; }
                int nbytes = (nl < 4) ? 16384 : 1024;
                size_t woff = (nl == 0) ? 0 : (311296 + (size_t)(nl - 1) * 131072);
                const char* srcp = (const char*)wp + woff + (size_t)nks * nbytes;
                char* dstp = (char*)&sW[cur ^ 1][0];
                for (int off = wv * 1024; off < nbytes; off += 8192)
                    gload_lds16(srcp + off + (ln << 4), dstp + off);
            }

            // compute on resident chunk sW[cur]
            if (layer < 4) {
                const f16* wbuf = &sW[cur][0];
                half8 a[4], b[2];
                #pragma unroll
                for (int t = 0; t < 2; ++t) {
                    int n = (wv * 2 + t) * 16 + lo;
                    b[t] = *(const half8*)&wbuf[hi * 2048 + n * 8];
                }
                #pragma unroll
                for (int m = 0; m < 4; ++m)
                    a[m] = *(const half8*)&src_act[(m * 16 + lo) * src_str + ks * 32 + hi * 8];
                #pragma unroll
                for (int m = 0; m < 4; ++m) {
                    #pragma unroll
                    for (int t = 0; t < 2; ++t)
                        acc[m][t] = __builtin_amdgcn_mfma_f32_16x16x32_f16(a[m], b[t], acc[m][t], 0, 0, 0);
                }
            } else if (wv == 0) {
                const f16* wbuf = &sW[cur][0];
                half8 bf = *(const half8*)&wbuf[hi * 128 + lo * 8];
                #pragma unroll
                for (int m = 0; m < 4; ++m) {
                    half8 a = *(const half8*)&src_act[(m * 16 + lo) * HSTR + ks * 32 + hi * 8];
                    acc[m][0] = __builtin_amdgcn_mfma_f32_16x16x32_f16(a, bf, acc[m][0], 0, 0, 0);
                }
            }
            __syncthreads();   // drains staged chunk; orders buffer reuse
            cur ^= 1;
        }

        // epilogue: bias + ReLU -> next activation buffer (f16)
        if (layer < 4) {
            const float* bias = (layer == 0) ? b0 : (layer == 1) ? b1 : (layer == 2) ? b2 : b3;
            #pragma unroll
            for (int t = 0; t < 2; ++t) {
                int n = (wv * 2 + t) * 16 + lo;
                float bv = bias[n];
                #pragma unroll
                for (int m = 0; m < 4; ++m) {
                    #pragma unroll
                    for (int i = 0; i < 4; ++i) {
                        int r = m * 16 + hi * 4 + i;
                        float v = fmaxf(acc[m][t][i] + bv, 0.f);
                        dst_act[r * HSTR + n] = (f16)v;
                    }
                }
            }
        } else if (wv == 0) {
            float bv = (lo < 3) ? b4[lo] : 0.f;
            if (lo < 4) {
                #pragma unroll
                for (int m = 0; m < 4; ++m) {
                    #pragma unroll
                    for (int i = 0; i < 4; ++i) {
                        int r = m * 16 + hi * 4 + i;
                        sPred[r * 4 + lo] = acc[m][0][i] + bv;
                    }
                }
            }
        }
        __syncthreads();   // epilogue writes visible before next layer reads

        f16* ns = dst_act;
        dst_act = (dst_act == sH) ? sX : sH;
        src_act = ns; src_str = HSTR;
    }

    // ---- local-ensemble combine (wave 0): pred_s weighted by area[s^3]/tot ----
    if (tid < 48) {
        int qloc = tid / 3;
        int ch = tid - qloc * 3;
        int rb = qloc * 4;
        float a0 = sArea[rb + 0], a1 = sArea[rb + 1], a2 = sArea[rb + 2], a3 = sArea[rb + 3];
        float tot = a0 + a1 + a2 + a3;
        float v = sPred[(rb + 0) * 4 + ch] * (a3 / tot)
                + sPred[(rb + 1) * 4 + ch] * (a2 / tot)
                + sPred[(rb + 2) * 4 + ch] * (a1 / tot)
                + sPred[(rb + 3) * 4 + ch] * (a0 / tot);
        out[ch * 65536 + blockIdx.x * 16 + qloc] = v;
    }
}

extern "C" void kernel_launch(void* const* d_in, const int* in_sizes, int n_in,
                              void* d_out, int out_size, void* d_ws, size_t ws_size,
                              hipStream_t stream) {
    const float* feat  = (const float*)d_in[0];
    const float* mask  = (const float*)d_in[1];
    const float* coord = (const float*)d_in[3];
    const float* W0 = (const float*)d_in[4];
    const float* b0 = (const float*)d_in[5];
    const float* W1 = (const float*)d_in[6];
    const float* b1 = (const float*)d_in[7];
    const float* W2 = (const float*)d_in[8];
    const float* b2 = (const float*)d_in[9];
    const float* W3 = (const float*)d_in[10];
    const float* b3 = (const float*)d_in[11];
    const float* W4 = (const float*)d_in[12];
    const float* b4 = (const float*)d_in[13];
    f16* wp = (f16*)d_ws;
    float* outp = (float*)d_out;

    prep_weights<<<(WP_TOTAL_HALFS + 255) / 256, 256, 0, stream>>>(W0, W1, W2, W3, W4, wp);
    liif_kernel<<<4096, NTHREADS, 0, stream>>>(feat, mask, coord, b0, b1, b2, b3, b4, wp, outp);
}

// Round 2
// 333.428 us; speedup vs baseline: 3.3003x; 3.3003x over previous
//
#include <hip/hip_runtime.h>

typedef _Float16 f16;
typedef _Float16 half8 __attribute__((ext_vector_type(8)));
typedef float f32x4 __attribute__((ext_vector_type(4)));

#define NTHREADS 512
#define HSTR 264          // halfs per activation row (256 used + 8 pad; 528B stride = 2-way bank alias, free)
#define XSTR 616          // halfs per u_gemm input row (608 used; 16B-aligned stride)

// d_ws layout (bytes):
//  [0, 311296)        packed W0  [76 k0][256 n][8]  f16
//  [311296, 704512)   packed W1..W3  3 x [32 k0][256 n][8] f16 (contiguous = 24 x 16KB chunks)
//  [704512, 712704)   packed W4  [32 k0][16 n][8] f16
//  [712704, 9101312)  U table [16384 cells][256] f16
#define WP_TOTAL_HALFS 356352
#define U_OFF_BYTES 712704

__device__ __forceinline__ void gload_lds16(const void* g, void* l) {
    __builtin_amdgcn_global_load_lds(
        (const __attribute__((address_space(1))) unsigned int*)g,
        (__attribute__((address_space(3))) unsigned int*)l, 16, 0, 0);
}

__device__ __forceinline__ void stage_chunk(const char* src, void* dst, int nbytes, int wv, int ln) {
    for (int off = wv * 1024; off < nbytes; off += 8192)
        gload_lds16(src + off + (ln << 4), (char*)dst + off);
}

__global__ void prep_weights(const float* __restrict__ W0, const float* __restrict__ W1,
                             const float* __restrict__ W2, const float* __restrict__ W3,
                             const float* __restrict__ W4, f16* __restrict__ wp) {
    int idx = blockIdx.x * 256 + threadIdx.x;
    if (idx >= WP_TOTAL_HALFS) return;
    float v = 0.f;
    if (idx < 155648) {                       // L0: k0 in [0,76), N=256
        int k0 = idx >> 11;
        int rem = idx & 2047;
        int n = rem >> 3, j = rem & 7;
        int k = k0 * 8 + j;
        if (k < 587) v = W0[k * 256 + n];
    } else if (idx < 352256) {                // L1..L3
        int local = idx - 155648;
        int l = local >> 16;
        int ll = local & 65535;
        int k0 = ll >> 11;
        int rem = ll & 2047;
        int n = rem >> 3, j = rem & 7;
        int k = k0 * 8 + j;
        const float* W = (l == 0) ? W1 : (l == 1) ? W2 : W3;
        v = W[k * 256 + n];
    } else {                                  // L4: N padded 3->16
        int local = idx - 352256;
        int k0 = local >> 7;
        int rem = local & 127;
        int n = rem >> 3, j = rem & 7;
        int k = k0 * 8 + j;
        if (n < 3) v = W4[k * 3 + n];
    }
    wp[idx] = (f16)v;
}

// ---- U-table GEMM: U[cell][n] = sum_{k<585} unfold[cell][k] * W0[k][n] + b0[n] ----
__global__ __launch_bounds__(NTHREADS, 2)
void u_gemm(const float* __restrict__ feat, const float* __restrict__ mask,
            const float* __restrict__ b0, const f16* __restrict__ wp,
            f16* __restrict__ U) {
    __shared__ __align__(16) f16 sX[64 * XSTR];
    __shared__ __align__(16) f16 sW[2][8192];

    const int tid = threadIdx.x;
    const int wv  = tid >> 6;
    const int ln  = tid & 63;
    const int lo  = ln & 15;
    const int hi  = ln >> 4;

    const int cell0 = blockIdx.x * 64;       // 64 consecutive cells, same grid row
    const int y  = cell0 >> 7;
    const int x0 = cell0 & 127;

    stage_chunk((const char*)wp, &sW[0][0], 16384, wv, ln);

    // gather: thread (r = tid&63, part = tid>>6); fully coalesced over r
    {
        int r = tid & 63;
        int part = tid >> 6;
        #pragma unroll
        for (int o = 0; o < 9; ++o) {
            int ki = o / 3, kj = o % 3;
            int yy = y + ki - 1;
            int xx = x0 + r + kj - 1;
            bool ok = ((unsigned)yy < 128u) && ((unsigned)xx < 128u);
            for (int c = part; c < 65; c += 8) {
                float v = 0.f;
                if (ok) v = (c < 64) ? feat[(c << 14) + (yy << 7) + xx] : mask[(yy << 7) + xx];
                sX[r * XSTR + c * 9 + o] = (f16)v;
            }
        }
    }
    if (tid < 64) {
        for (int k = 585; k < 608; ++k) sX[tid * XSTR + k] = (f16)0.f;  // rel rows excluded here
    }
    __syncthreads();

    f32x4 acc[4][2];
    #pragma unroll
    for (int m = 0; m < 4; ++m) { acc[m][0] = f32x4{0,0,0,0}; acc[m][1] = f32x4{0,0,0,0}; }

    for (int g = 0; g < 19; ++g) {
        if (g + 1 < 19)
            stage_chunk((const char*)wp + (g + 1) * 16384, &sW[(g + 1) & 1][0], 16384, wv, ln);
        const f16* wbuf = &sW[g & 1][0];
        half8 a[4], b[2];
        #pragma unroll
        for (int t = 0; t < 2; ++t)
            b[t] = *(const half8*)&wbuf[hi * 2048 + ((wv * 2 + t) * 16 + lo) * 8];
        #pragma unroll
        for (int m = 0; m < 4; ++m)
            a[m] = *(const half8*)&sX[(m * 16 + lo) * XSTR + g * 32 + hi * 8];
        #pragma unroll
        for (int m = 0; m < 4; ++m) {
            #pragma unroll
            for (int t = 0; t < 2; ++t)
                acc[m][t] = __builtin_amdgcn_mfma_f32_16x16x32_f16(a[m], b[t], acc[m][t], 0, 0, 0);
        }
        __syncthreads();
    }

    #pragma unroll
    for (int t = 0; t < 2; ++t) {
        int n = (wv * 2 + t) * 16 + lo;
        float bv = b0[n];
        #pragma unroll
        for (int m = 0; m < 4; ++m) {
            #pragma unroll
            for (int i = 0; i < 4; ++i) {
                int cell = cell0 + m * 16 + hi * 4 + i;
                U[cell * 256 + n] = (f16)(acc[m][t][i] + bv);
            }
        }
    }
}

// ---- main: per (query,shift) row, h0 from U-table + rel axpy, then L1..L4 ----
__global__ __launch_bounds__(NTHREADS, 4)
void liif_main(const float* __restrict__ coord, const float* __restrict__ W0,
               const float* __restrict__ b1, const float* __restrict__ b2,
               const float* __restrict__ b3, const float* __restrict__ b4,
               const f16* __restrict__ wp, const f16* __restrict__ U,
               float* __restrict__ out) {
    __shared__ __align__(16) f16 sAct[64 * HSTR];     // 33792 B
    __shared__ __align__(16) f16 sW[2][8192];         // 32768 B
    __shared__ float sRel0[64], sRel1[64], sArea[64];
    __shared__ int   sCell[64];
    __shared__ float sPred[64 * 4];

    const int tid = threadIdx.x;
    const int wv  = tid >> 6;
    const int ln  = tid & 63;
    const int lo  = ln & 15;
    const int hi  = ln >> 4;

    const char* wbase = (const char*)wp + 311296;     // L1 chunk 0

    stage_chunk(wbase, &sW[0][0], 16384, wv, ln);

    // meta (exact reference index math, fp32)
    if (tid < 64) {
        int r = tid;
        int R = blockIdx.x * 64 + r;
        int q = R >> 2, s = R & 3;
        float c0 = coord[q * 2 + 0];
        float c1 = coord[q * 2 + 1];
        float vx = (s & 2) ? 1.0f : -1.0f;
        float vy = (s & 1) ? 1.0f : -1.0f;
        const float rxy = 0.0078125f;
        const float LOC = (float)(-1.0 + 1e-6);
        const float HIC = (float)( 1.0 - 1e-6);
        float cy = fminf(fmaxf(c0 + vx * rxy + 1e-6f, LOC), HIC);
        float cx = fminf(fmaxf(c1 + vy * rxy + 1e-6f, LOC), HIC);
        int iy = (int)rintf(((cy + 1.0f) * 128.0f - 1.0f) * 0.5f);
        int ix = (int)rintf(((cx + 1.0f) * 128.0f - 1.0f) * 0.5f);
        iy = min(max(iy, 0), 127);
        ix = min(max(ix, 0), 127);
        float qy = -1.0f + ((float)(2 * iy) + 1.0f) * rxy;
        float qx = -1.0f + ((float)(2 * ix) + 1.0f) * rxy;
        float rel0 = (c0 - qy) * 128.0f;
        float rel1 = (c1 - qx) * 128.0f;
        sCell[r] = iy * 128 + ix;
        sRel0[r] = rel0;
        sRel1[r] = rel1;
        sArea[r] = fabsf(rel0 * rel1) + 1e-9f;
    }
    __syncthreads();

    // h0 = relu(U[cell] + rel0*W0[585] + rel1*W0[586])   (b0 folded into U)
    {
        int r = tid >> 3, j = tid & 7;
        int cell = sCell[r];
        float r0 = sRel0[r], r1 = sRel1[r];
        const f16* ub = U + cell * 256 + j * 32;
        const float* wa = W0 + 585 * 256 + j * 32;
        const float* wb = W0 + 586 * 256 + j * 32;
        #pragma unroll
        for (int q = 0; q < 4; ++q) {
            half8 u = *(const half8*)(ub + q * 8);
            half8 hv;
            #pragma unroll
            for (int e = 0; e < 8; ++e) {
                float h = (float)u[e] + r0 * wa[q * 8 + e] + r1 * wb[q * 8 + e];
                hv[e] = (f16)fmaxf(h, 0.f);
            }
            *(half8*)&sAct[r * HSTR + j * 32 + q * 8] = hv;
        }
    }
    __syncthreads();

    f32x4 acc[4][2];
    #pragma unroll
    for (int m = 0; m < 4; ++m) { acc[m][0] = f32x4{0,0,0,0}; acc[m][1] = f32x4{0,0,0,0}; }

    for (int g = 0; g <= 24; ++g) {
        // stage next chunk (chunks 0..23 = 16KB L1-3; chunk 24 = 8KB W4)
        if (g < 24) {
            int nc = g + 1;
            stage_chunk(wbase + nc * 16384, &sW[nc & 1][0], (nc == 24) ? 8192 : 16384, wv, ln);
        }

        if (g < 24) {
            const f16* wbuf = &sW[g & 1][0];
            int ks = g & 7;
            half8 a[4], b[2];
            #pragma unroll
            for (int t = 0; t < 2; ++t)
                b[t] = *(const half8*)&wbuf[hi * 2048 + ((wv * 2 + t) * 16 + lo) * 8];
            #pragma unroll
            for (int m = 0; m < 4; ++m)
                a[m] = *(const half8*)&sAct[(m * 16 + lo) * HSTR + ks * 32 + hi * 8];
            #pragma unroll
            for (int m = 0; m < 4; ++m) {
                #pragma unroll
                for (int t = 0; t < 2; ++t)
                    acc[m][t] = __builtin_amdgcn_mfma_f32_16x16x32_f16(a[m], b[t], acc[m][t], 0, 0, 0);
            }
        } else if (wv < 4) {
            // L4: wave w computes rows [w*16, w*16+16), N=16 (3 used)
            const f16* wbuf = &sW[0][0];   // chunk 24 -> buffer 0
            #pragma unroll
            for (int ks = 0; ks < 8; ++ks) {
                half8 bf = *(const half8*)&wbuf[(ks * 4 + hi) * 128 + lo * 8];
                half8 a  = *(const half8*)&sAct[(wv * 16 + lo) * HSTR + ks * 32 + hi * 8];
                acc[0][0] = __builtin_amdgcn_mfma_f32_16x16x32_f16(a, bf, acc[0][0], 0, 0, 0);
            }
        }
        __syncthreads();

        if (g == 7 || g == 15 || g == 23) {
            const float* bias = (g == 7) ? b1 : (g == 15) ? b2 : b3;
            #pragma unroll
            for (int t = 0; t < 2; ++t) {
                int n = (wv * 2 + t) * 16 + lo;
                float bv = bias[n];
                #pragma unroll
                for (int m = 0; m < 4; ++m) {
                    #pragma unroll
                    for (int i = 0; i < 4; ++i) {
                        int r = m * 16 + hi * 4 + i;
                        sAct[r * HSTR + n] = (f16)fmaxf(acc[m][t][i] + bv, 0.f);
                    }
                    acc[m][t] = f32x4{0,0,0,0};
                }
            }
            __syncthreads();
        }
    }

    // L4 epilogue -> sPred
    if (wv < 4 && lo < 4) {
        float bv = (lo < 3) ? b4[lo] : 0.f;
        #pragma unroll
        for (int i = 0; i < 4; ++i) {
            int r = wv * 16 + hi * 4 + i;
            sPred[r * 4 + lo] = acc[0][0][i] + bv;
        }
    }
    __syncthreads();

    // local-ensemble combine: pred_s weighted by area[s^3]/tot
    if (tid < 48) {
        int qloc = tid / 3;
        int ch = tid - qloc * 3;
        int rb = qloc * 4;
        float a0 = sArea[rb + 0], a1 = sArea[rb + 1], a2 = sArea[rb + 2], a3 = sArea[rb + 3];
        float tot = a0 + a1 + a2 + a3;
        float v = sPred[(rb + 0) * 4 + ch] * (a3 / tot)
                + sPred[(rb + 1) * 4 + ch] * (a2 / tot)
                + sPred[(rb + 2) * 4 + ch] * (a1 / tot)
                + sPred[(rb + 3) * 4 + ch] * (a0 / tot);
        out[ch * 65536 + blockIdx.x * 16 + qloc] = v;
    }
}

extern "C" void kernel_launch(void* const* d_in, const int* in_sizes, int n_in,
                              void* d_out, int out_size, void* d_ws, size_t ws_size,
                              hipStream_t stream) {
    const float* feat  = (const float*)d_in[0];
    const float* mask  = (const float*)d_in[1];
    const float* coord = (const float*)d_in[3];
    const float* W0 = (const float*)d_in[4];
    const float* b0 = (const float*)d_in[5];
    const float* W1 = (const float*)d_in[6];
    const float* b1 = (const float*)d_in[7];
    const float* W2 = (const float*)d_in[8];
    const float* b2 = (const float*)d_in[9];
    const float* W3 = (const float*)d_in[10];
    const float* b3 = (const float*)d_in[11];
    const float* W4 = (const float*)d_in[12];
    const float* b4 = (const float*)d_in[13];
    f16* wp = (f16*)d_ws;
    f16* U  = (f16*)((char*)d_ws + U_OFF_BYTES);
    float* outp = (float*)d_out;

    prep_weights<<<(WP_TOTAL_HALFS + 255) / 256, 256, 0, stream>>>(W0, W1, W2, W3, W4, wp);
    u_gemm<<<256, NTHREADS, 0, stream>>>(feat, mask, b0, wp, U);
    liif_main<<<4096, NTHREADS, 0, stream>>>(coord, W0, b1, b2, b3, b4, wp, U, outp);
}

// Round 6
// 307.344 us; speedup vs baseline: 3.5804x; 1.0849x over previous
//
#include <hip/hip_runtime.h>

typedef _Float16 f16;
typedef _Float16 half8 __attribute__((ext_vector_type(8)));
typedef _Float16 half4 __attribute__((ext_vector_type(4)));
typedef float f32x4 __attribute__((ext_vector_type(4)));

#define NTHREADS 512
#define XSTR 616

// d_ws layout (bytes):
//  [0, 311296)        W0 pack  [76 k0][256 n][8] f16          (u_gemm B-operand)
//  [311296, 704512)   WT: 24 chunks x [256 n][32 k] f16 (16KB each); chunk = (layer-1)*8 + k/32, TRANSPOSED
//  [704512, 712704)   W4T [16 n][256 k] f16 (n>=3 zero)
//  [712704, 9101312)  U table [16384 cells][256] f16
#define WP_TOTAL_HALFS 356352
#define WT_OFF_H   155648
#define W4_OFF_H   352256
#define U_OFF_BYTES 712704

__device__ __forceinline__ void gload_lds16(const void* g, void* l) {
    __builtin_amdgcn_global_load_lds(
        (const __attribute__((address_space(1))) unsigned int*)g,
        (__attribute__((address_space(3))) unsigned int*)l, 16, 0, 0);
}

__device__ __forceinline__ void stage_chunk(const char* src, void* dst, int nbytes, int wv, int ln) {
    for (int off = wv * 1024; off < nbytes; off += 8192)
        gload_lds16(src + off + (ln << 4), (char*)dst + off);
}

__global__ void prep_weights(const float* __restrict__ W0, const float* __restrict__ W1,
                             const float* __restrict__ W2, const float* __restrict__ W3,
                             const float* __restrict__ W4, f16* __restrict__ wp) {
    int idx = blockIdx.x * 256 + threadIdx.x;
    if (idx >= WP_TOTAL_HALFS) return;
    float v = 0.f;
    if (idx < WT_OFF_H) {                     // L0 pack (u_gemm), unchanged layout
        int k0 = idx >> 11;
        int rem = idx & 2047;
        int n = rem >> 3, j = rem & 7;
        int k = k0 * 8 + j;
        if (k < 587) v = W0[k * 256 + n];
    } else if (idx < W4_OFF_H) {              // WT: transposed [n][k] chunks
        int local = idx - WT_OFF_H;
        int kk = local & 31;
        int rowi = local >> 5;                // chunk*256 + n
        int n = rowi & 255;
        int lc = rowi >> 8;                   // 0..23
        int l = lc >> 3, c = lc & 7;
        int k = c * 32 + kk;
        const float* W = (l == 0) ? W1 : (l == 1) ? W2 : W3;
        v = W[k * 256 + n];
    } else {                                  // W4T [16][256]
        int local = idx - W4_OFF_H;
        int n = local >> 8, k = local & 255;
        v = (n < 3) ? W4[k * 3 + n] : 0.f;
    }
    wp[idx] = (f16)v;
}

// ---- U-table GEMM (unchanged, proven): U[cell][n] = unfold[cell] @ W0[:585] + b0 ----
__global__ __launch_bounds__(NTHREADS, 2)
void u_gemm(const float* __restrict__ feat, const float* __restrict__ mask,
            const float* __restrict__ b0, const f16* __restrict__ wp,
            f16* __restrict__ U) {
    __shared__ __align__(16) f16 sX[64 * XSTR];
    __shared__ __align__(16) f16 sW[2][8192];

    const int tid = threadIdx.x;
    const int wv  = tid >> 6;
    const int ln  = tid & 63;
    const int lo  = ln & 15;
    const int hi  = ln >> 4;

    const int cell0 = blockIdx.x * 64;
    const int y  = cell0 >> 7;
    const int x0 = cell0 & 127;

    stage_chunk((const char*)wp, &sW[0][0], 16384, wv, ln);

    {
        int r = tid & 63;
        int part = tid >> 6;
        #pragma unroll
        for (int o = 0; o < 9; ++o) {
            int ki = o / 3, kj = o % 3;
            int yy = y + ki - 1;
            int xx = x0 + r + kj - 1;
            bool ok = ((unsigned)yy < 128u) && ((unsigned)xx < 128u);
            for (int c = part; c < 65; c += 8) {
                float v = 0.f;
                if (ok) v = (c < 64) ? feat[(c << 14) + (yy << 7) + xx] : mask[(yy << 7) + xx];
                sX[r * XSTR + c * 9 + o] = (f16)v;
            }
        }
    }
    if (tid < 64) {
        for (int k = 585; k < 608; ++k) sX[tid * XSTR + k] = (f16)0.f;
    }
    __syncthreads();

    f32x4 acc[4][2];
    #pragma unroll
    for (int m = 0; m < 4; ++m) { acc[m][0] = f32x4{0,0,0,0}; acc[m][1] = f32x4{0,0,0,0}; }

    for (int g = 0; g < 19; ++g) {
        if (g + 1 < 19)
            stage_chunk((const char*)wp + (g + 1) * 16384, &sW[(g + 1) & 1][0], 16384, wv, ln);
        const f16* wbuf = &sW[g & 1][0];
        half8 a[4], b[2];
        #pragma unroll
        for (int t = 0; t < 2; ++t)
            b[t] = *(const half8*)&wbuf[hi * 2048 + ((wv * 2 + t) * 16 + lo) * 8];
        #pragma unroll
        for (int m = 0; m < 4; ++m)
            a[m] = *(const half8*)&sX[(m * 16 + lo) * XSTR + g * 32 + hi * 8];
        #pragma unroll
        for (int m = 0; m < 4; ++m) {
            #pragma unroll
            for (int t = 0; t < 2; ++t)
                acc[m][t] = __builtin_amdgcn_mfma_f32_16x16x32_f16(a[m], b[t], acc[m][t], 0, 0, 0);
        }
        __syncthreads();
    }

    #pragma unroll
    for (int t = 0; t < 2; ++t) {
        int n = (wv * 2 + t) * 16 + lo;
        float bv = b0[n];
        #pragma unroll
        for (int m = 0; m < 4; ++m) {
            #pragma unroll
            for (int i = 0; i < 4; ++i) {
                int cell = cell0 + m * 16 + hi * 4 + i;
                U[cell * 256 + n] = (f16)(acc[m][t][i] + bv);
            }
        }
    }
}

// ---- main: swapped-operand MFMA (W^T as A, act as B), swizzled act tile, weights from L1/L2 ----
__global__ __launch_bounds__(NTHREADS, 4)
void liif_main(const float* __restrict__ coord, const float* __restrict__ W0,
               const float* __restrict__ b1, const float* __restrict__ b2,
               const float* __restrict__ b3, const float* __restrict__ b4,
               const f16* __restrict__ wp, const f16* __restrict__ U,
               float* __restrict__ out) {
    __shared__ __align__(16) f16 sAct[128 * 256];      // 64KB, XOR-swizzled rows (stride 512B)
    __shared__ float sRel0[128], sRel1[128], sArea[128];
    __shared__ int   sCell[128];
    __shared__ float sPred[128 * 4];

    const int tid = threadIdx.x;
    const int wv  = tid >> 6;
    const int ln  = tid & 63;
    const int lo  = ln & 15;
    const int hi  = ln >> 4;
    const int ng  = wv & 3;      // n-group (64 cols of W out of 256)
    const int qg  = wv >> 2;     // q-group (64 of 128 rows)

    // meta: exact reference fp32 index math
    if (tid < 128) {
        int r = tid;
        int R = blockIdx.x * 128 + r;
        int q = R >> 2, s = R & 3;
        float c0 = coord[q * 2 + 0];
        float c1 = coord[q * 2 + 1];
        float vx = (s & 2) ? 1.0f : -1.0f;
        float vy = (s & 1) ? 1.0f : -1.0f;
        const float rxy = 0.0078125f;
        const float LOC = (float)(-1.0 + 1e-6);
        const float HIC = (float)( 1.0 - 1e-6);
        float cy = fminf(fmaxf(c0 + vx * rxy + 1e-6f, LOC), HIC);
        float cx = fminf(fmaxf(c1 + vy * rxy + 1e-6f, LOC), HIC);
        int iy = (int)rintf(((cy + 1.0f) * 128.0f - 1.0f) * 0.5f);
        int ix = (int)rintf(((cx + 1.0f) * 128.0f - 1.0f) * 0.5f);
        iy = min(max(iy, 0), 127);
        ix = min(max(ix, 0), 127);
        float qy = -1.0f + ((float)(2 * iy) + 1.0f) * rxy;
        float qx = -1.0f + ((float)(2 * ix) + 1.0f) * rxy;
        float rel0 = (c0 - qy) * 128.0f;
        float rel1 = (c1 - qx) * 128.0f;
        sCell[r] = iy * 128 + ix;
        sRel0[r] = rel0;
        sRel1[r] = rel1;
        sArea[r] = fabsf(rel0 * rel1) + 1e-9f;
    }
    __syncthreads();

    // h0[row][n] = relu(U[cell][n] + rel0*W0[585][n] + rel1*W0[586][n]) -> swizzled sAct
    {
        int row = tid >> 2, p = tid & 3;
        int cell = sCell[row];
        float r0 = sRel0[row], r1 = sRel1[row];
        const half8* up = (const half8*)(U + cell * 256 + p * 64);
        const float* wa = W0 + 585 * 256 + p * 64;
        const float* wb = W0 + 586 * 256 + p * 64;
        char* rowbase = (char*)sAct + row * 512;
        int swz = (row & 7) << 4;
        #pragma unroll
        for (int e = 0; e < 8; ++e) {
            half8 u = up[e];
            half8 hv;
            #pragma unroll
            for (int j = 0; j < 8; ++j) {
                float h = (float)u[j] + r0 * wa[e * 8 + j] + r1 * wb[e * 8 + j];
                hv[j] = (f16)fmaxf(h, 0.f);
            }
            *(half8*)(rowbase + ((p * 128 + e * 16) ^ swz)) = hv;
        }
    }
    __syncthreads();

    // ---- layers 1..3: 24 K=32 chunks, epilogue at g=7,15,23 ----
    const f16* wT = wp + WT_OFF_H;
    const f16* aBase = wT + ng * 2048 + lo * 32 + hi * 8;   // + chunk*8192 + ti*512
    const int rowb = qg * 64 + lo;                          // + tj*16
    const int swzb = (lo & 7) << 4;                         // row&7 invariant under +16
    const char* actb = (const char*)sAct + rowb * 512;

    f32x4 acc[4][4];
    #pragma unroll
    for (int i = 0; i < 4; ++i)
        #pragma unroll
        for (int j = 0; j < 4; ++j) acc[i][j] = f32x4{0,0,0,0};

    #define LOADA(A, c) { \
        const f16* p_ = aBase + (c) * 8192; \
        A[0] = *(const half8*)(p_); \
        A[1] = *(const half8*)(p_ + 512); \
        A[2] = *(const half8*)(p_ + 1024); \
        A[3] = *(const half8*)(p_ + 1536); }

    #define LOADB(B, g) { \
        int byte_ = ((((g) & 7) * 4 + hi) << 4) ^ swzb; \
        B[0] = *(const half8*)(actb + byte_); \
        B[1] = *(const half8*)(actb + 8192 + byte_); \
        B[2] = *(const half8*)(actb + 16384 + byte_); \
        B[3] = *(const half8*)(actb + 24576 + byte_); }

    #define MF(A, B) { \
        _Pragma("unroll") \
        for (int ni = 0; ni < 4; ++ni) { \
            _Pragma("unroll") \
            for (int qj = 0; qj < 4; ++qj) \
                acc[ni][qj] = __builtin_amdgcn_mfma_f32_16x16x32_f16(A[ni], B[qj], acc[ni][qj], 0, 0, 0); } }

    #define EPI(bias) { \
        __syncthreads(); \
        _Pragma("unroll") \
        for (int ni = 0; ni < 4; ++ni) { \
            int nb_ = ng * 64 + ni * 16 + hi * 4; \
            f32x4 bv_ = *(const f32x4*)((bias) + nb_); \
            _Pragma("unroll") \
            for (int qj = 0; qj < 4; ++qj) { \
                int q_ = qg * 64 + qj * 16 + lo; \
                half4 h_; \
                _Pragma("unroll") \
                for (int r = 0; r < 4; ++r) h_[r] = (f16)fmaxf(acc[ni][qj][r] + bv_[r], 0.f); \
                *(half4*)((char*)sAct + q_ * 512 + ((nb_ * 2) ^ ((q_ & 7) << 4))) = h_; \
                acc[ni][qj] = f32x4{0,0,0,0}; \
            } } \
        __syncthreads(); }

    half8 a0[4], a1[4], b[4];
    LOADA(a0, 0);
    for (int gg = 0; gg < 12; ++gg) {
        int g = gg * 2;
        LOADA(a1, g + 1);
        LOADB(b, g);
        MF(a0, b);
        if (g + 2 < 24) LOADA(a0, g + 2);
        LOADB(b, g + 1);
        MF(a1, b);
        if (g + 1 == 7)       EPI(b1)
        else if (g + 1 == 15) EPI(b2)
        else if (g + 1 == 23) EPI(b3)
    }

    // ---- L4: wave wv handles queries wv*16+lo; A = W4T from global ----
    {
        f32x4 acc4 = f32x4{0,0,0,0};
        const f16* w4 = wp + W4_OFF_H + lo * 256 + hi * 8;
        const int row4 = wv * 16 + lo;
        const char* act4 = (const char*)sAct + row4 * 512;
        const int swz4 = (row4 & 7) << 4;
        #pragma unroll
        for (int ks = 0; ks < 8; ++ks) {
            half8 a = *(const half8*)(w4 + ks * 32);
            half8 bb = *(const half8*)(act4 + ((((ks * 4 + hi) << 4)) ^ swz4));
            acc4 = __builtin_amdgcn_mfma_f32_16x16x32_f16(a, bb, acc4, 0, 0, 0);
        }
        if (hi == 0) {
            #pragma unroll
            for (int r = 0; r < 3; ++r) sPred[row4 * 4 + r] = acc4[r] + b4[r];
        }
    }
    __syncthreads();

    // local-ensemble combine
    if (tid < 96) {
        int qloc = tid / 3;
        int ch = tid - qloc * 3;
        int rb = qloc * 4;
        float a0_ = sArea[rb + 0], a1_ = sArea[rb + 1], a2_ = sArea[rb + 2], a3_ = sArea[rb + 3];
        float tot = a0_ + a1_ + a2_ + a3_;
        float v = sPred[(rb + 0) * 4 + ch] * (a3_ / tot)
                + sPred[(rb + 1) * 4 + ch] * (a2_ / tot)
                + sPred[(rb + 2) * 4 + ch] * (a1_ / tot)
                + sPred[(rb + 3) * 4 + ch] * (a0_ / tot);
        out[ch * 65536 + blockIdx.x * 32 + qloc] = v;
    }
}

extern "C" void kernel_launch(void* const* d_in, const int* in_sizes, int n_in,
                              void* d_out, int out_size, void* d_ws, size_t ws_size,
                              hipStream_t stream) {
    const float* feat  = (const float*)d_in[0];
    const float* mask  = (const float*)d_in[1];
    const float* coord = (const float*)d_in[3];
    const float* W0 = (const float*)d_in[4];
    const float* b0 = (const float*)d_in[5];
    const float* W1 = (const float*)d_in[6];
    const float* b1 = (const float*)d_in[7];
    const float* W2 = (const float*)d_in[8];
    const float* b2 = (const float*)d_in[9];
    const float* W3 = (const float*)d_in[10];
    const float* b3 = (const float*)d_in[11];
    const float* W4 = (const float*)d_in[12];
    const float* b4 = (const float*)d_in[13];
    f16* wp = (f16*)d_ws;
    f16* U  = (f16*)((char*)d_ws + U_OFF_BYTES);
    float* outp = (float*)d_out;

    prep_weights<<<(WP_TOTAL_HALFS + 255) / 256, 256, 0, stream>>>(W0, W1, W2, W3, W4, wp);
    u_gemm<<<256, NTHREADS, 0, stream>>>(feat, mask, b0, wp, U);
    liif_main<<<2048, NTHREADS, 0, stream>>>(coord, W0, b1, b2, b3, b4, wp, U, outp);
}

// Round 11
// 302.155 us; speedup vs baseline: 3.6419x; 1.0172x over previous
//
#include <hip/hip_runtime.h>

typedef _Float16 f16;
typedef _Float16 half8 __attribute__((ext_vector_type(8)));
typedef _Float16 half4 __attribute__((ext_vector_type(4)));
typedef float f32x4 __attribute__((ext_vector_type(4)));

#define NTHREADS 512
#define XSTR 616

// d_ws layout (bytes):
//  [0, 311296)        W0 pack  [76 k0][256 n][8] f16          (u_gemm B-operand)
//  [311296, 704512)   WT: 24 chunks x [256 n][32 k] f16 (16KB each); chunk = (layer-1)*8 + k/32, TRANSPOSED
//  [704512, 712704)   W4T [16 n][256 k] f16 (n>=3 zero)
//  [712704, 9101312)  U table [16384 cells][256] f16
#define WP_TOTAL_HALFS 356352
#define WT_OFF_H   155648
#define W4_OFF_H   352256
#define U_OFF_BYTES 712704

__device__ __forceinline__ void gload_lds16(const void* g, void* l) {
    __builtin_amdgcn_global_load_lds(
        (const __attribute__((address_space(1))) unsigned int*)g,
        (__attribute__((address_space(3))) unsigned int*)l, 16, 0, 0);
}

__device__ __forceinline__ void stage_chunk(const char* src, void* dst, int nbytes, int wv, int ln) {
    for (int off = wv * 1024; off < nbytes; off += 8192)
        gload_lds16(src + off + (ln << 4), (char*)dst + off);
}

__global__ void prep_weights(const float* __restrict__ W0, const float* __restrict__ W1,
                             const float* __restrict__ W2, const float* __restrict__ W3,
                             const float* __restrict__ W4, f16* __restrict__ wp) {
    int idx = blockIdx.x * 256 + threadIdx.x;
    if (idx >= WP_TOTAL_HALFS) return;
    float v = 0.f;
    if (idx < WT_OFF_H) {                     // L0 pack (u_gemm), unchanged layout
        int k0 = idx >> 11;
        int rem = idx & 2047;
        int n = rem >> 3, j = rem & 7;
        int k = k0 * 8 + j;
        if (k < 587) v = W0[k * 256 + n];
    } else if (idx < W4_OFF_H) {              // WT: transposed [n][k] chunks
        int local = idx - WT_OFF_H;
        int kk = local & 31;
        int rowi = local >> 5;                // chunk*256 + n
        int n = rowi & 255;
        int lc = rowi >> 8;                   // 0..23
        int l = lc >> 3, c = lc & 7;
        int k = c * 32 + kk;
        const float* W = (l == 0) ? W1 : (l == 1) ? W2 : W3;
        v = W[k * 256 + n];
    } else {                                  // W4T [16][256]
        int local = idx - W4_OFF_H;
        int n = local >> 8, k = local & 255;
        v = (n < 3) ? W4[k * 3 + n] : 0.f;
    }
    wp[idx] = (f16)v;
}

// ---- U-table GEMM (unchanged, proven): U[cell][n] = unfold[cell] @ W0[:585] + b0 ----
__global__ __launch_bounds__(NTHREADS, 2)
void u_gemm(const float* __restrict__ feat, const float* __restrict__ mask,
            const float* __restrict__ b0, const f16* __restrict__ wp,
            f16* __restrict__ U) {
    __shared__ __align__(16) f16 sX[64 * XSTR];
    __shared__ __align__(16) f16 sW[2][8192];

    const int tid = threadIdx.x;
    const int wv  = tid >> 6;
    const int ln  = tid & 63;
    const int lo  = ln & 15;
    const int hi  = ln >> 4;

    const int cell0 = blockIdx.x * 64;
    const int y  = cell0 >> 7;
    const int x0 = cell0 & 127;

    stage_chunk((const char*)wp, &sW[0][0], 16384, wv, ln);

    {
        int r = tid & 63;
        int part = tid >> 6;
        #pragma unroll
        for (int o = 0; o < 9; ++o) {
            int ki = o / 3, kj = o % 3;
            int yy = y + ki - 1;
            int xx = x0 + r + kj - 1;
            bool ok = ((unsigned)yy < 128u) && ((unsigned)xx < 128u);
            for (int c = part; c < 65; c += 8) {
                float v = 0.f;
                if (ok) v = (c < 64) ? feat[(c << 14) + (yy << 7) + xx] : mask[(yy << 7) + xx];
                sX[r * XSTR + c * 9 + o] = (f16)v;
            }
        }
    }
    if (tid < 64) {
        for (int k = 585; k < 608; ++k) sX[tid * XSTR + k] = (f16)0.f;
    }
    __syncthreads();

    f32x4 acc[4][2];
    #pragma unroll
    for (int m = 0; m < 4; ++m) { acc[m][0] = f32x4{0,0,0,0}; acc[m][1] = f32x4{0,0,0,0}; }

    for (int g = 0; g < 19; ++g) {
        if (g + 1 < 19)
            stage_chunk((const char*)wp + (g + 1) * 16384, &sW[(g + 1) & 1][0], 16384, wv, ln);
        half8 a[4], b[2];
        #pragma unroll
        for (int t = 0; t < 2; ++t)
            b[t] = *(const half8*)&sW[g & 1][hi * 2048 + ((wv * 2 + t) * 16 + lo) * 8];
        #pragma unroll
        for (int m = 0; m < 4; ++m)
            a[m] = *(const half8*)&sX[(m * 16 + lo) * XSTR + g * 32 + hi * 8];
        #pragma unroll
        for (int m = 0; m < 4; ++m) {
            #pragma unroll
            for (int t = 0; t < 2; ++t)
                acc[m][t] = __builtin_amdgcn_mfma_f32_16x16x32_f16(a[m], b[t], acc[m][t], 0, 0, 0);
        }
        __syncthreads();
    }

    #pragma unroll
    for (int t = 0; t < 2; ++t) {
        int n = (wv * 2 + t) * 16 + lo;
        float bv = b0[n];
        #pragma unroll
        for (int m = 0; m < 4; ++m) {
            #pragma unroll
            for (int i = 0; i < 4; ++i) {
                int cell = cell0 + m * 16 + hi * 4 + i;
                U[cell * 256 + n] = (f16)(acc[m][t][i] + bv);
            }
        }
    }
}

// ---- main: swapped-operand MFMA (W^T as A, act as B), swizzled act tile, weights from L1/L2 ----
// Single-buffered A fragments: live regs ~116 <= 128-reg cap at 2 blocks/CU -> no scratch spill.
__global__ __launch_bounds__(NTHREADS, 4)
void liif_main(const float* __restrict__ coord, const float* __restrict__ W0,
               const float* __restrict__ b1, const float* __restrict__ b2,
               const float* __restrict__ b3, const float* __restrict__ b4,
               const f16* __restrict__ wp, const f16* __restrict__ U,
               float* __restrict__ out) {
    __shared__ __align__(16) f16 sAct[128 * 256];      // 64KB, XOR-swizzled rows (stride 512B)
    __shared__ float sRel0[128], sRel1[128], sArea[128];
    __shared__ int   sCell[128];
    __shared__ float sPred[128 * 4];

    const int tid = threadIdx.x;
    const int wv  = tid >> 6;
    const int ln  = tid & 63;
    const int lo  = ln & 15;
    const int hi  = ln >> 4;
    const int ng  = wv & 3;      // n-group (64 cols of W out of 256)
    const int qg  = wv >> 2;     // q-group (64 of 128 rows)

    // meta: exact reference fp32 index math
    if (tid < 128) {
        int r = tid;
        int R = blockIdx.x * 128 + r;
        int q = R >> 2, s = R & 3;
        float c0 = coord[q * 2 + 0];
        float c1 = coord[q * 2 + 1];
        float vx = (s & 2) ? 1.0f : -1.0f;
        float vy = (s & 1) ? 1.0f : -1.0f;
        const float rxy = 0.0078125f;
        const float LOC = (float)(-1.0 + 1e-6);
        const float HIC = (float)( 1.0 - 1e-6);
        float cy = fminf(fmaxf(c0 + vx * rxy + 1e-6f, LOC), HIC);
        float cx = fminf(fmaxf(c1 + vy * rxy + 1e-6f, LOC), HIC);
        int iy = (int)rintf(((cy + 1.0f) * 128.0f - 1.0f) * 0.5f);
        int ix = (int)rintf(((cx + 1.0f) * 128.0f - 1.0f) * 0.5f);
        iy = min(max(iy, 0), 127);
        ix = min(max(ix, 0), 127);
        float qy = -1.0f + ((float)(2 * iy) + 1.0f) * rxy;
        float qx = -1.0f + ((float)(2 * ix) + 1.0f) * rxy;
        float rel0 = (c0 - qy) * 128.0f;
        float rel1 = (c1 - qx) * 128.0f;
        sCell[r] = iy * 128 + ix;
        sRel0[r] = rel0;
        sRel1[r] = rel1;
        sArea[r] = fabsf(rel0 * rel1) + 1e-9f;
    }
    __syncthreads();

    // h0[row][n] = relu(U[cell][n] + rel0*W0[585][n] + rel1*W0[586][n]) -> swizzled sAct
    {
        int row = tid >> 2, p = tid & 3;
        int cell = sCell[row];
        float r0 = sRel0[row], r1 = sRel1[row];
        const half8* up = (const half8*)(U + cell * 256 + p * 64);
        const float* wa = W0 + 585 * 256 + p * 64;
        const float* wb = W0 + 586 * 256 + p * 64;
        char* rowbase = (char*)sAct + row * 512;
        int swz = (row & 7) << 4;
        #pragma unroll
        for (int e = 0; e < 8; ++e) {
            half8 u = up[e];
            half8 hv;
            #pragma unroll
            for (int j = 0; j < 8; ++j) {
                float h = (float)u[j] + r0 * wa[e * 8 + j] + r1 * wb[e * 8 + j];
                hv[j] = (f16)fmaxf(h, 0.f);
            }
            *(half8*)(rowbase + ((p * 128 + e * 16) ^ swz)) = hv;
        }
    }
    __syncthreads();

    // ---- layers 1..3: 24 K=32 chunks, epilogue at g=7,15,23 ----
    const f16* wT = wp + WT_OFF_H;
    const f16* aBase = wT + ng * 2048 + lo * 32 + hi * 8;   // + chunk*8192 + ti*512
    const int rowb = qg * 64 + lo;                          // + tj*16
    const int swzb = (lo & 7) << 4;                         // row&7 invariant under +16
    const char* actb = (const char*)sAct + rowb * 512;

    f32x4 acc[4][4];
    #pragma unroll
    for (int i = 0; i < 4; ++i)
        #pragma unroll
        for (int j = 0; j < 4; ++j) acc[i][j] = f32x4{0,0,0,0};

    #define LOADA(A, c) { \
        const f16* p_ = aBase + (c) * 8192; \
        A[0] = *(const half8*)(p_); \
        A[1] = *(const half8*)(p_ + 512); \
        A[2] = *(const half8*)(p_ + 1024); \
        A[3] = *(const half8*)(p_ + 1536); }

    #define LOADB(B, g) { \
        int byte_ = ((((g) & 7) * 4 + hi) << 4) ^ swzb; \
        B[0] = *(const half8*)(actb + byte_); \
        B[1] = *(const half8*)(actb + 8192 + byte_); \
        B[2] = *(const half8*)(actb + 16384 + byte_); \
        B[3] = *(const half8*)(actb + 24576 + byte_); }

    #define MF(A, B) { \
        _Pragma("unroll") \
        for (int ni = 0; ni < 4; ++ni) { \
            _Pragma("unroll") \
            for (int qj = 0; qj < 4; ++qj) \
                acc[ni][qj] = __builtin_amdgcn_mfma_f32_16x16x32_f16(A[ni], B[qj], acc[ni][qj], 0, 0, 0); } }

    #define EPI(bias) { \
        __syncthreads(); \
        _Pragma("unroll") \
        for (int ni = 0; ni < 4; ++ni) { \
            int nb_ = ng * 64 + ni * 16 + hi * 4; \
            f32x4 bv_ = *(const f32x4*)((bias) + nb_); \
            _Pragma("unroll") \
            for (int qj = 0; qj < 4; ++qj) { \
                int q_ = qg * 64 + qj * 16 + lo; \
                half4 h_; \
                _Pragma("unroll") \
                for (int r = 0; r < 4; ++r) h_[r] = (f16)fmaxf(acc[ni][qj][r] + bv_[r], 0.f); \
                *(half4*)((char*)sAct + q_ * 512 + ((nb_ * 2) ^ ((q_ & 7) << 4))) = h_; \
                acc[ni][qj] = f32x4{0,0,0,0}; \
            } } \
        __syncthreads(); }

    half8 a[4], b[4];
    for (int g = 0; g < 24; ++g) {
        LOADA(a, g);
        LOADB(b, g);
        MF(a, b);
        if (g == 7)       EPI(b1)
        else if (g == 15) EPI(b2)
        else if (g == 23) EPI(b3)
    }

    // ---- L4: wave wv handles queries wv*16+lo; A = W4T from global ----
    {
        f32x4 acc4 = f32x4{0,0,0,0};
        const f16* w4 = wp + W4_OFF_H + lo * 256 + hi * 8;
        const int row4 = wv * 16 + lo;
        const char* act4 = (const char*)sAct + row4 * 512;
        const int swz4 = (row4 & 7) << 4;
        #pragma unroll
        for (int ks = 0; ks < 8; ++ks) {
            half8 aw = *(const half8*)(w4 + ks * 32);
            half8 bb = *(const half8*)(act4 + ((((ks * 4 + hi) << 4)) ^ swz4));
            acc4 = __builtin_amdgcn_mfma_f32_16x16x32_f16(aw, bb, acc4, 0, 0, 0);
        }
        if (hi == 0) {
            #pragma unroll
            for (int r = 0; r < 3; ++r) sPred[row4 * 4 + r] = acc4[r] + b4[r];
        }
    }
    __syncthreads();

    // local-ensemble combine
    if (tid < 96) {
        int qloc = tid / 3;
        int ch = tid - qloc * 3;
        int rb = qloc * 4;
        float a0_ = sArea[rb + 0], a1_ = sArea[rb + 1], a2_ = sArea[rb + 2], a3_ = sArea[rb + 3];
        float tot = a0_ + a1_ + a2_ + a3_;
        float v = sPred[(rb + 0) * 4 + ch] * (a3_ / tot)
                + sPred[(rb + 1) * 4 + ch] * (a2_ / tot)
                + sPred[(rb + 2) * 4 + ch] * (a1_ / tot)
                + sPred[(rb + 3) * 4 + ch] * (a0_ / tot);
        out[ch * 65536 + blockIdx.x * 32 + qloc] = v;
    }
}

extern "C" void kernel_launch(void* const* d_in, const int* in_sizes, int n_in,
                              void* d_out, int out_size, void* d_ws, size_t ws_size,
                              hipStream_t stream) {
    const float* feat  = (const float*)d_in[0];
    const float* mask  = (const float*)d_in[1];
    const float* coord = (const float*)d_in[3];
    const float* W0 = (const float*)d_in[4];
    const float* b0 = (const float*)d_in[5];
    const float* W1 = (const float*)d_in[6];
    const float* b1 = (const float*)d_in[7];
    const float* W2 = (const float*)d_in[8];
    const float* b2 = (const float*)d_in[9];
    const float* W3 = (const float*)d_in[10];
    const float* b3 = (const float*)d_in[11];
    const float* W4 = (const float*)d_in[12];
    const float* b4 = (const float*)d_in[13];
    f16* wp = (f16*)d_ws;
    f16* U  = (f16*)((char*)d_ws + U_OFF_BYTES);
    float* outp = (float*)d_out;

    prep_weights<<<(WP_TOTAL_HALFS + 255) / 256, 256, 0, stream>>>(W0, W1, W2, W3, W4, wp);
    u_gemm<<<256, NTHREADS, 0, stream>>>(feat, mask, b0, wp, U);
    liif_main<<<2048, NTHREADS, 0, stream>>>(coord, W0, b1, b2, b3, b4, wp, U, outp);
}